// Round 1
// baseline (5838.535 us; speedup 1.0000x reference)
//
#include <hip/hip_runtime.h>
#include <hip/hip_bf16.h>

#define Bsz  16384
#define Din  1024
#define Dout 1024
#define Hdim 2048
#define Ecnt 8

__device__ __forceinline__ float bf2f(unsigned short u) {
    unsigned int v = ((unsigned int)u) << 16;
    float f;
    __builtin_memcpy(&f, &v, 4);
    return f;
}
__device__ __forceinline__ unsigned short f2bf(float f) {
    unsigned int x;
    __builtin_memcpy(&x, &f, 4);
    unsigned int lsb = (x >> 16) & 1u;
    x += 0x7fffu + lsb;           // round-to-nearest-even
    return (unsigned short)(x >> 16);
}

// ---------------- Router: logits -> softmax -> top-2 -> buckets ----------------
__global__ __launch_bounds__(256) void router_kernel(
    const float* __restrict__ x, const float* __restrict__ rW,
    const float* __restrict__ rb, float* __restrict__ probs_out,
    int* __restrict__ cnt, int* __restrict__ bucket, float* __restrict__ gates)
{
    __shared__ float s_rw[Ecnt * Din];   // 32 KiB
    int t = threadIdx.x;
    for (int i = t; i < Ecnt * Din; i += 256) s_rw[i] = rW[i];
    __syncthreads();

    int wid = t >> 6, lane = t & 63;
    int token = blockIdx.x * 4 + wid;

    float acc[8] = {0,0,0,0,0,0,0,0};
    const float* xrow = x + (size_t)token * Din;
    for (int i = 0; i < Din / 64; i++) {
        int d = lane + 64 * i;
        float xv = xrow[d];
        #pragma unroll
        for (int e = 0; e < 8; e++) acc[e] += xv * s_rw[e * Din + d];
    }
    #pragma unroll
    for (int e = 0; e < 8; e++) {
        #pragma unroll
        for (int m = 1; m < 64; m <<= 1) acc[e] += __shfl_xor(acc[e], m, 64);
    }
    // every lane now holds the full 8 logits
    float p[8], mx = -1e30f;
    #pragma unroll
    for (int e = 0; e < 8; e++) { p[e] = acc[e] + rb[e]; mx = fmaxf(mx, p[e]); }
    float s = 0.f;
    #pragma unroll
    for (int e = 0; e < 8; e++) { p[e] = expf(p[e] - mx); s += p[e]; }
    float inv = 1.f / s;
    #pragma unroll
    for (int e = 0; e < 8; e++) p[e] *= inv;

    if (lane == 0) {
        float* po = probs_out + (size_t)token * Ecnt;
        #pragma unroll
        for (int e = 0; e < 8; e++) po[e] = p[e];
        // top-2 (ties -> lower index, matching jax.lax.top_k)
        int i0 = 0; float v0 = p[0];
        #pragma unroll
        for (int e = 1; e < 8; e++) if (p[e] > v0) { v0 = p[e]; i0 = e; }
        int i1 = -1; float v1 = -1e30f;
        #pragma unroll
        for (int e = 0; e < 8; e++) if (e != i0 && p[e] > v1) { v1 = p[e]; i1 = e; }
        float invs = 1.f / (v0 + v1);
        int pos0 = atomicAdd(&cnt[i0], 1);
        bucket[i0 * Bsz + pos0] = token * 2;
        gates [i0 * Bsz + pos0] = v0 * invs;
        int pos1 = atomicAdd(&cnt[i1], 1);
        bucket[i1 * Bsz + pos1] = token * 2 + 1;
        gates [i1 * Bsz + pos1] = v1 * invs;
    }
}

// ---------------- GEMM1: h[r,:] = relu(x[b,:] @ W1[e].T + b1[e]) -> bf16 ----------------
__global__ __launch_bounds__(256) void gemm1_kernel(
    const float* __restrict__ x, const float* __restrict__ W1,
    const float* __restrict__ b1, const int* __restrict__ cnt,
    const int* __restrict__ bucket, unsigned short* __restrict__ hbuf)
{
    int e = blockIdx.z;
    int count = cnt[e];
    int t0 = blockIdx.y * 64;
    if (t0 >= count) return;
    int hc0 = blockIdx.x * 64;

    __shared__ float As[64][17];
    __shared__ float Bs[64][17];
    __shared__ int rows[64];

    int t = threadIdx.x;
    if (t < 64) {
        int pos = t0 + t;
        rows[t] = (pos < count) ? bucket[e * Bsz + pos] : -1;
    }
    __syncthreads();

    float acc[4][4] = {};
    int tx = t & 15, ty = t >> 4;
    int lrow = t >> 2;           // 0..63
    int lk   = (t & 3) * 4;      // 0,4,8,12

    int r = rows[lrow];
    const float* aptr = (r >= 0) ? (x + (size_t)(r >> 1) * Din) : nullptr;
    const float* bptr = W1 + (size_t)e * Hdim * Din + (size_t)(hc0 + lrow) * Din;

    for (int k0 = 0; k0 < Din; k0 += 16) {
        float4 av = make_float4(0.f, 0.f, 0.f, 0.f);
        if (aptr) av = *(const float4*)(aptr + k0 + lk);
        float4 bv = *(const float4*)(bptr + k0 + lk);
        __syncthreads();
        As[lrow][lk + 0] = av.x; As[lrow][lk + 1] = av.y;
        As[lrow][lk + 2] = av.z; As[lrow][lk + 3] = av.w;
        Bs[lrow][lk + 0] = bv.x; Bs[lrow][lk + 1] = bv.y;
        Bs[lrow][lk + 2] = bv.z; Bs[lrow][lk + 3] = bv.w;
        __syncthreads();
        #pragma unroll
        for (int kk = 0; kk < 16; kk++) {
            float a0 = As[ty * 4 + 0][kk], a1 = As[ty * 4 + 1][kk];
            float a2 = As[ty * 4 + 2][kk], a3 = As[ty * 4 + 3][kk];
            float b0 = Bs[tx * 4 + 0][kk], b1v = Bs[tx * 4 + 1][kk];
            float b2v = Bs[tx * 4 + 2][kk], b3 = Bs[tx * 4 + 3][kk];
            acc[0][0] += a0 * b0;  acc[0][1] += a0 * b1v;
            acc[0][2] += a0 * b2v; acc[0][3] += a0 * b3;
            acc[1][0] += a1 * b0;  acc[1][1] += a1 * b1v;
            acc[1][2] += a1 * b2v; acc[1][3] += a1 * b3;
            acc[2][0] += a2 * b0;  acc[2][1] += a2 * b1v;
            acc[2][2] += a2 * b2v; acc[2][3] += a2 * b3;
            acc[3][0] += a3 * b0;  acc[3][1] += a3 * b1v;
            acc[3][2] += a3 * b2v; acc[3][3] += a3 * b3;
        }
    }

    #pragma unroll
    for (int i = 0; i < 4; i++) {
        int rr = rows[ty * 4 + i];
        if (rr < 0) continue;
        unsigned short* hrow = hbuf + (size_t)rr * Hdim;
        #pragma unroll
        for (int j = 0; j < 4; j++) {
            int hc = hc0 + tx * 4 + j;
            float v = acc[i][j] + b1[e * Hdim + hc];
            v = fmaxf(v, 0.f);
            hrow[hc] = f2bf(v);
        }
    }
}

// ---------------- GEMM2: out[b,:] += gate * (h[r,:] @ W2[e].T + b2[e]) ----------------
__global__ __launch_bounds__(256) void gemm2_kernel(
    const unsigned short* __restrict__ hbuf, const float* __restrict__ W2,
    const float* __restrict__ b2, const int* __restrict__ cnt,
    const int* __restrict__ bucket, const float* __restrict__ gates,
    float* __restrict__ out)
{
    int e = blockIdx.z;
    int count = cnt[e];
    int t0 = blockIdx.y * 64;
    if (t0 >= count) return;
    int o0 = blockIdx.x * 64;

    __shared__ float As[64][17];
    __shared__ float Bs[64][17];
    __shared__ int rows[64];
    __shared__ float gts[64];

    int t = threadIdx.x;
    if (t < 64) {
        int pos = t0 + t;
        bool v = pos < count;
        rows[t] = v ? bucket[e * Bsz + pos] : -1;
        gts[t]  = v ? gates[e * Bsz + pos] : 0.f;
    }
    __syncthreads();

    float acc[4][4] = {};
    int tx = t & 15, ty = t >> 4;
    int lrow = t >> 2;
    int lk   = (t & 3) * 4;

    int r = rows[lrow];
    const unsigned short* aptr = (r >= 0) ? (hbuf + (size_t)r * Hdim) : nullptr;
    const float* bptr = W2 + (size_t)e * Dout * Hdim + (size_t)(o0 + lrow) * Hdim;

    for (int k0 = 0; k0 < Hdim; k0 += 16) {
        ushort4 hv = make_ushort4(0, 0, 0, 0);
        if (aptr) hv = *(const ushort4*)(aptr + k0 + lk);
        float4 bv = *(const float4*)(bptr + k0 + lk);
        __syncthreads();
        As[lrow][lk + 0] = bf2f(hv.x); As[lrow][lk + 1] = bf2f(hv.y);
        As[lrow][lk + 2] = bf2f(hv.z); As[lrow][lk + 3] = bf2f(hv.w);
        Bs[lrow][lk + 0] = bv.x; Bs[lrow][lk + 1] = bv.y;
        Bs[lrow][lk + 2] = bv.z; Bs[lrow][lk + 3] = bv.w;
        __syncthreads();
        #pragma unroll
        for (int kk = 0; kk < 16; kk++) {
            float a0 = As[ty * 4 + 0][kk], a1 = As[ty * 4 + 1][kk];
            float a2 = As[ty * 4 + 2][kk], a3 = As[ty * 4 + 3][kk];
            float b0 = Bs[tx * 4 + 0][kk], b1v = Bs[tx * 4 + 1][kk];
            float b2v = Bs[tx * 4 + 2][kk], b3 = Bs[tx * 4 + 3][kk];
            acc[0][0] += a0 * b0;  acc[0][1] += a0 * b1v;
            acc[0][2] += a0 * b2v; acc[0][3] += a0 * b3;
            acc[1][0] += a1 * b0;  acc[1][1] += a1 * b1v;
            acc[1][2] += a1 * b2v; acc[1][3] += a1 * b3;
            acc[2][0] += a2 * b0;  acc[2][1] += a2 * b1v;
            acc[2][2] += a2 * b2v; acc[2][3] += a2 * b3;
            acc[3][0] += a3 * b0;  acc[3][1] += a3 * b1v;
            acc[3][2] += a3 * b2v; acc[3][3] += a3 * b3;
        }
    }

    #pragma unroll
    for (int i = 0; i < 4; i++) {
        int rr = rows[ty * 4 + i];
        if (rr < 0) continue;
        int b = rr >> 1;
        float g = gts[ty * 4 + i];
        #pragma unroll
        for (int j = 0; j < 4; j++) {
            int o = o0 + tx * 4 + j;
            float val = g * (acc[i][j] + b2[e * Dout + o]);
            atomicAdd(&out[(size_t)b * Dout + o], val);
        }
    }
}

extern "C" void kernel_launch(void* const* d_in, const int* in_sizes, int n_in,
                              void* d_out, int out_size, void* d_ws, size_t ws_size,
                              hipStream_t stream) {
    const float* x   = (const float*)d_in[0];
    const float* rW  = (const float*)d_in[1];
    const float* rb  = (const float*)d_in[2];
    const float* W1  = (const float*)d_in[3];
    const float* b1  = (const float*)d_in[4];
    const float* W2  = (const float*)d_in[5];
    const float* b2  = (const float*)d_in[6];
    float* out   = (float*)d_out;
    float* probs = out + (size_t)Bsz * Dout;

    char* ws = (char*)d_ws;
    int*   cnt    = (int*)ws;                                  // 32 B
    int*   bucket = (int*)(ws + 256);                          // 512 KiB
    float* gates  = (float*)(ws + (1u << 20));                 // 512 KiB
    unsigned short* hbuf = (unsigned short*)(ws + (2u << 20)); // 32768 x 2048 bf16 = 128 MiB

    hipMemsetAsync(cnt, 0, Ecnt * sizeof(int), stream);
    hipMemsetAsync(out, 0, (size_t)Bsz * Dout * sizeof(float), stream);

    router_kernel<<<Bsz / 4, 256, 0, stream>>>(x, rW, rb, probs, cnt, bucket, gates);

    dim3 g1(Hdim / 64, Bsz / 64, Ecnt);
    gemm1_kernel<<<g1, 256, 0, stream>>>(x, W1, b1, cnt, bucket, hbuf);

    dim3 g2(Dout / 64, Bsz / 64, Ecnt);
    gemm2_kernel<<<g2, 256, 0, stream>>>(hbuf, W2, b2, cnt, bucket, gates, out);
}

// Round 3
// 1076.902 us; speedup vs baseline: 5.4216x; 5.4216x over previous
//
#include <hip/hip_runtime.h>
#include <hip/hip_bf16.h>

#define Bsz  16384
#define Din  1024
#define Dout 1024
#define Hdim 2048
#define Ecnt 8

typedef _Float16 f16;
typedef _Float16 f16x8 __attribute__((ext_vector_type(8)));
typedef _Float16 f16x4 __attribute__((ext_vector_type(4)));
typedef float    f32x4 __attribute__((ext_vector_type(4)));

#define AS_GLOBAL __attribute__((address_space(1)))
#define AS_LDS    __attribute__((address_space(3)))

__device__ __forceinline__ void async_copy16(const void* gptr, void* lptr) {
    __builtin_amdgcn_global_load_lds(
        (const AS_GLOBAL unsigned int*)gptr,
        (AS_LDS unsigned int*)lptr, 16, 0, 0);
}

// ---------------- fp32 -> fp16 cast ----------------
__global__ __launch_bounds__(256) void cast_kernel(
    const float* __restrict__ in, f16* __restrict__ out)
{
    int i = (blockIdx.x * 256 + threadIdx.x) * 4;
    float4 v = *(const float4*)(in + i);
    f16x4 o;
    o.x = (f16)v.x; o.y = (f16)v.y; o.z = (f16)v.z; o.w = (f16)v.w;
    *(f16x4*)(out + i) = o;
}

// ---------------- Router: logits -> softmax -> top-2 -> buckets ----------------
__global__ __launch_bounds__(256) void router_kernel(
    const float* __restrict__ x, const float* __restrict__ rW,
    const float* __restrict__ rb, float* __restrict__ probs_out,
    int* __restrict__ cnt, int* __restrict__ bucket, float* __restrict__ gates)
{
    __shared__ float s_rw[Ecnt * Din];   // 32 KiB
    int t = threadIdx.x;
    for (int i = t; i < Ecnt * Din; i += 256) s_rw[i] = rW[i];
    __syncthreads();

    int wid = t >> 6, lane = t & 63;
    int token = blockIdx.x * 4 + wid;

    float acc[8] = {0,0,0,0,0,0,0,0};
    const float* xrow = x + (size_t)token * Din;
    for (int i = 0; i < Din / 64; i++) {
        int d = lane + 64 * i;
        float xv = xrow[d];
        #pragma unroll
        for (int e = 0; e < 8; e++) acc[e] += xv * s_rw[e * Din + d];
    }
    #pragma unroll
    for (int e = 0; e < 8; e++) {
        #pragma unroll
        for (int m = 1; m < 64; m <<= 1) acc[e] += __shfl_xor(acc[e], m, 64);
    }
    float p[8], mx = -1e30f;
    #pragma unroll
    for (int e = 0; e < 8; e++) { p[e] = acc[e] + rb[e]; mx = fmaxf(mx, p[e]); }
    float s = 0.f;
    #pragma unroll
    for (int e = 0; e < 8; e++) { p[e] = expf(p[e] - mx); s += p[e]; }
    float inv = 1.f / s;
    #pragma unroll
    for (int e = 0; e < 8; e++) p[e] *= inv;

    if (lane == 0) {
        float* po = probs_out + (size_t)token * Ecnt;
        #pragma unroll
        for (int e = 0; e < 8; e++) po[e] = p[e];
        int i0 = 0; float v0 = p[0];
        #pragma unroll
        for (int e = 1; e < 8; e++) if (p[e] > v0) { v0 = p[e]; i0 = e; }
        int i1 = -1; float v1 = -1e30f;
        #pragma unroll
        for (int e = 0; e < 8; e++) if (e != i0 && p[e] > v1) { v1 = p[e]; i1 = e; }
        float invs = 1.f / (v0 + v1);
        int pos0 = atomicAdd(&cnt[i0], 1);
        bucket[i0 * Bsz + pos0] = token * 2;
        gates [i0 * Bsz + pos0] = v0 * invs;
        int pos1 = atomicAdd(&cnt[i1], 1);
        bucket[i1 * Bsz + pos1] = token * 2 + 1;
        gates [i1 * Bsz + pos1] = v1 * invs;
    }
}

// ---------------- MFMA grouped GEMM (m97 structure) ----------------
// G1: h[r,:] = relu(x_f16[r>>1,:] @ W1[e].T + b1[e]) -> hbuf (f16)
// G2: out[r>>1,:] += gate[r] * (hbuf[r,:] @ W2[e].T + b2[e])   (atomicAdd)
template<int Kd, bool G1>
__global__ __launch_bounds__(256) void moe_gemm(
    const f16* __restrict__ A, const f16* __restrict__ Wt,
    const float* __restrict__ bias, const int* __restrict__ cnt,
    const int* __restrict__ bucket, const float* __restrict__ gates,
    f16* __restrict__ hbuf, float* __restrict__ out, int Ndim)
{
    int e = blockIdx.z;
    int count = min(cnt[e], Bsz);
    int m0 = blockIdx.y * 128;
    if (m0 >= count) return;
    int n0 = blockIdx.x * 128;

    __shared__ alignas(16) f16 As[128 * 32];
    __shared__ alignas(16) f16 Bs[128 * 32];
    __shared__ int   s_rows[128];
    __shared__ float s_gates[128];

    int t = threadIdx.x;
    if (t < 128) {
        int pos = min(m0 + t, count - 1);
        s_rows[t] = bucket[e * Bsz + pos];
        if constexpr (!G1) s_gates[t] = gates[e * Bsz + pos];
    }
    __syncthreads();

    int wave = t >> 6, lane = t & 63;
    int scol = (lane & 3) * 8;            // f16 elems within row (16 B chunks)

    // per-lane global source pointers: 2 staging instrs each for A and B
    const f16* agp[2];
    const f16* bgp[2];
    #pragma unroll
    for (int j = 0; j < 2; j++) {
        int srow = wave * 32 + j * 16 + (lane >> 2);
        int r = s_rows[srow];
        size_t arow = G1 ? (size_t)(r >> 1) : (size_t)r;
        agp[j] = A + arow * Kd + scol;
        bgp[j] = Wt + ((size_t)e * Ndim + (n0 + srow)) * (size_t)Kd + scol;
    }

    int m_w = (wave >> 1) * 64;           // wave's 64x64 sub-tile
    int n_w = (wave & 1) * 64;
    int frow = lane & 15;
    int fk   = (lane >> 4) * 8;

    f32x4 acc[4][4] = {};

    for (int k0 = 0; k0 < Kd; k0 += 32) {
        #pragma unroll
        for (int j = 0; j < 2; j++) {
            async_copy16(agp[j], As + (wave * 32 + j * 16) * 32);
            async_copy16(bgp[j], Bs + (wave * 32 + j * 16) * 32);
            agp[j] += 32; bgp[j] += 32;
        }
        __syncthreads();   // compiler drains vmcnt before s_barrier

        f16x8 af[4], bfr[4];
        #pragma unroll
        for (int i = 0; i < 4; i++) {
            af[i]  = *(const f16x8*)(As + (m_w + i * 16 + frow) * 32 + fk);
            bfr[i] = *(const f16x8*)(Bs + (n_w + i * 16 + frow) * 32 + fk);
        }
        #pragma unroll
        for (int i = 0; i < 4; i++)
            #pragma unroll
            for (int jj = 0; jj < 4; jj++)
                acc[i][jj] = __builtin_amdgcn_mfma_f32_16x16x32_f16(
                    af[i], bfr[jj], acc[i][jj], 0, 0, 0);
        __syncthreads();   // frag reads done before next stage overwrites
    }

    // epilogue: D row = m = (lane>>4)*4 + reg (+16*i), D col = n = lane&15 (+16*jj)
    float bv[4];
    #pragma unroll
    for (int jj = 0; jj < 4; jj++)
        bv[jj] = bias[e * Ndim + n0 + n_w + jj * 16 + frow];

    #pragma unroll
    for (int i = 0; i < 4; i++) {
        int mbase = m_w + i * 16 + (lane >> 4) * 4;
        #pragma unroll
        for (int reg = 0; reg < 4; reg++) {
            int m = mbase + reg;
            if (m0 + m >= count) continue;
            int r = s_rows[m];
            if constexpr (G1) {
                f16* hrow = hbuf + (size_t)r * Hdim;
                #pragma unroll
                for (int jj = 0; jj < 4; jj++) {
                    int n = n0 + n_w + jj * 16 + frow;
                    float v = acc[i][jj][reg] + bv[jj];
                    hrow[n] = (f16)fmaxf(v, 0.f);
                }
            } else {
                int token = r >> 1;
                float g = s_gates[m];
                #pragma unroll
                for (int jj = 0; jj < 4; jj++) {
                    int n = n0 + n_w + jj * 16 + frow;
                    float v = g * (acc[i][jj][reg] + bv[jj]);
                    atomicAdd(&out[(size_t)token * Dout + n], v);
                }
            }
        }
    }
}

extern "C" void kernel_launch(void* const* d_in, const int* in_sizes, int n_in,
                              void* d_out, int out_size, void* d_ws, size_t ws_size,
                              hipStream_t stream) {
    const float* x   = (const float*)d_in[0];
    const float* rW  = (const float*)d_in[1];
    const float* rb  = (const float*)d_in[2];
    const float* W1  = (const float*)d_in[3];
    const float* b1  = (const float*)d_in[4];
    const float* W2  = (const float*)d_in[5];
    const float* b2  = (const float*)d_in[6];
    float* out   = (float*)d_out;
    float* probs = out + (size_t)Bsz * Dout;

    // Workspace layout (fixed from R2: bucket/gates are 512 KiB EACH)
    char* ws = (char*)d_ws;
    int*   cnt    = (int*)ws;                            // 32 B
    int*   bucket = (int*)(ws + 0x1000);                 // 512 KiB (Ecnt*Bsz*4)
    float* gates  = (float*)(ws + 0x90000);              // 512 KiB
    f16*   x16    = (f16*)(ws + 0x200000);               // 32 MiB
    f16*   w16    = (f16*)(ws + 0x2200000);              // 32 MiB (W1, then W2)
    f16*   hbuf   = (f16*)(ws + 0x4200000);              // 128 MiB
    // total = 0xC200000 = 194 MiB

    hipMemsetAsync(cnt, 0, Ecnt * sizeof(int), stream);
    hipMemsetAsync(out, 0, (size_t)Bsz * Dout * sizeof(float), stream);

    cast_kernel<<<(Bsz * Din) / 1024, 256, 0, stream>>>(x, x16);
    cast_kernel<<<(Ecnt * Hdim * Din) / 1024, 256, 0, stream>>>(W1, w16);

    router_kernel<<<Bsz / 4, 256, 0, stream>>>(x, rW, rb, probs, cnt, bucket, gates);

    dim3 g1(Hdim / 128, Bsz / 128, Ecnt);
    moe_gemm<Din, true><<<g1, 256, 0, stream>>>(
        x16, w16, b1, cnt, bucket, gates, hbuf, out, Hdim);

    // W2 cast reuses w16 (stream-ordered after gemm1)
    cast_kernel<<<(Ecnt * Dout * Hdim) / 1024, 256, 0, stream>>>(W2, w16);

    dim3 g2(Dout / 128, Bsz / 128, Ecnt);
    moe_gemm<Hdim, false><<<g2, 256, 0, stream>>>(
        hbuf, w16, b2, cnt, bucket, gates, hbuf, out, Dout);
}